// Round 1
// baseline (1893.883 us; speedup 1.0000x reference)
//
#include <hip/hip_runtime.h>
#include <hip/hip_bf16.h>

typedef unsigned short u16;
typedef unsigned int   u32;
typedef __attribute__((ext_vector_type(8))) __bf16 bf16x8;
typedef __attribute__((ext_vector_type(4))) float  f32x4;

#define NWIN   4096
#define SEQ    64
#define DIMC   384
#define NHEAD  12
#define HDIM   32
#define NROWS  262144      /* NWIN*SEQ */
#define NQKV   1152

__device__ __forceinline__ u16 f2bf(float f){
  u32 x = __float_as_uint(f);
  return (u16)((x + 0x7fffu + ((x >> 16) & 1u)) >> 16);   // RNE
}

__device__ __forceinline__ void gload_lds16(const u16* g, u16* l){
  __builtin_amdgcn_global_load_lds(
      (const __attribute__((address_space(1))) void*)g,
      (__attribute__((address_space(3))) void*)l, 16, 0, 0);
}

__device__ __forceinline__ f32x4 mfma_bf16(bf16x8 a, bf16x8 b, f32x4 c){
  return __builtin_amdgcn_mfma_f32_16x16x32_bf16(a, b, c, 0, 0, 0);
}

// ---------------- prep kernels ----------------
__global__ void prep_x(const float* __restrict__ x, u16* __restrict__ xb){
  size_t i = ((size_t)blockIdx.x * 256 + threadIdx.x) * 8;
  f32x4 a = *(const f32x4*)(x + i);
  f32x4 b = *(const f32x4*)(x + i + 4);
  union { u16 u[8]; bf16x8 v; } o;
  #pragma unroll
  for(int j=0;j<4;j++) o.u[j]   = f2bf(a[j]);
  #pragma unroll
  for(int j=0;j<4;j++) o.u[4+j] = f2bf(b[j]);
  *(bf16x8*)(xb + i) = o.v;
}

// transpose+convert weights, build biasT[h][n][m]
__global__ void prep_w(const float* __restrict__ qw, const float* __restrict__ pw,
                       const float* __restrict__ rpb, const int* __restrict__ rpi,
                       u16* __restrict__ wqT, u16* __restrict__ wpT,
                       float* __restrict__ biasT){
  int id = blockIdx.x * 256 + threadIdx.x;
  if (id < NQKV*DIMC){                      // qkv_wT[n][k] = qkv_w[k][n]
    int n = id / DIMC, k = id % DIMC;
    wqT[id] = f2bf(qw[(size_t)k*NQKV + n]);
  } else if (id < NQKV*DIMC + DIMC*DIMC){   // projT[n][k] = proj_w[k][n]
    int j = id - NQKV*DIMC;
    int n = j / DIMC, k = j % DIMC;
    wpT[j] = f2bf(pw[(size_t)k*DIMC + n]);
  } else {
    int j = id - (NQKV*DIMC + DIMC*DIMC);   // 0 .. 12*4096-1
    int h = j / 4096, nm = j % 4096;
    biasT[j] = rpb[rpi[nm]*NHEAD + h];
  }
}

// ---------------- GEMM: C[M x 128NB..] = A[M x 384] * Bt[N x 384]^T + bias ----------------
// EPI=0: bf16 out split into q/k/v regions.  EPI=1: fp32 out.
template<int NB, int EPI>
__global__ __launch_bounds__(256, 2) void gemm_bt(
    const u16* __restrict__ A, const u16* __restrict__ Bt,
    const float* __restrict__ bias,
    u16* __restrict__ oq, u16* __restrict__ okk, u16* __restrict__ ov,
    float* __restrict__ of)
{
  // tiles [128 rows][64 k] bf16, 16B-unit XOR swizzle: phys_u = u ^ (row&7)
  __shared__ u16 Al[2][8192];
  __shared__ u16 Bl[2][8192];
  const int bid = blockIdx.x;
  const int bm = bid / NB, bn = bid % NB;
  const size_t m0 = (size_t)bm * 128;
  const int n0 = bn * 128;
  const int tid = threadIdx.x, wv = tid >> 6, ln = tid & 63;
  const int wr = wv >> 1, wc = wv & 1;         // 2x2 waves, 64x64 per wave
  const int cl = ln & 15, q8 = ln >> 4;

  f32x4 acc[4][4];
  const f32x4 zero4 = {0.f,0.f,0.f,0.f};
  #pragma unroll
  for(int i=0;i<4;i++)
    #pragma unroll
    for(int j=0;j<4;j++) acc[i][j] = zero4;

  auto stage = [&](int bufi, int kt){
    #pragma unroll
    for(int c=0;c<4;c++){
      int un  = (wv*4+c)*64 + ln;        // linear 16B-unit index 0..1023
      int row = un >> 3;
      int u   = (un & 7) ^ (row & 7);    // logical unit stored at this phys slot
      gload_lds16(A  + (m0 + row)*DIMC + kt*64 + u*8, &Al[bufi][(wv*4+c)*512]);
      gload_lds16(Bt + (size_t)(n0 + row)*DIMC + kt*64 + u*8, &Bl[bufi][(wv*4+c)*512]);
    }
  };

  stage(0, 0);
  #pragma unroll
  for(int kt=0;kt<6;kt++){
    const int bufi = kt & 1;
    __syncthreads();                     // drains in-flight global_load_lds
    if (kt < 5) stage(bufi^1, kt+1);     // prefetch next tile into other buffer
    #pragma unroll
    for(int ks=0;ks<2;ks++){
      bf16x8 af[4], bfr[4];
      #pragma unroll
      for(int i=0;i<4;i++){
        int row = wr*64 + i*16 + cl;
        int u = (ks*4 + q8) ^ (row & 7);
        af[i] = *(const bf16x8*)&Al[bufi][row*64 + u*8];
      }
      #pragma unroll
      for(int j=0;j<4;j++){
        int row = wc*64 + j*16 + cl;
        int u = (ks*4 + q8) ^ (row & 7);
        bfr[j] = *(const bf16x8*)&Bl[bufi][row*64 + u*8];
      }
      #pragma unroll
      for(int i=0;i<4;i++)
        #pragma unroll
        for(int j=0;j<4;j++)
          acc[i][j] = mfma_bf16(af[i], bfr[j], acc[i][j]);
    }
  }

  float bj[4];
  #pragma unroll
  for(int j=0;j<4;j++) bj[j] = bias[n0 + wc*64 + j*16 + cl];

  if (EPI == 0){
    const int t = n0 / DIMC;                       // 0:q 1:k 2:v (128 | 384)
    const int lc0 = n0 - t*DIMC + wc*64 + cl;
    u16* dst = (t==0) ? oq : (t==1) ? okk : ov;
    #pragma unroll
    for(int i=0;i<4;i++){
      size_t r0 = m0 + wr*64 + i*16 + q8*4;
      #pragma unroll
      for(int j=0;j<4;j++)
        #pragma unroll
        for(int r=0;r<4;r++)
          dst[(r0 + r)*DIMC + lc0 + j*16] = f2bf(acc[i][j][r] + bj[j]);
    }
  } else {
    const int lc0 = n0 + wc*64 + cl;
    #pragma unroll
    for(int i=0;i<4;i++){
      size_t r0 = m0 + wr*64 + i*16 + q8*4;
      #pragma unroll
      for(int j=0;j<4;j++)
        #pragma unroll
        for(int r=0;r<4;r++)
          of[(r0 + r)*DIMC + lc0 + j*16] = acc[i][j][r] + bj[j];
    }
  }
}

// ---------------- fused window attention ----------------
// 1 block = 1 window, 4 waves, wave handles 3 heads.
__global__ __launch_bounds__(256, 1) void attn_win(
    const u16* __restrict__ Q, const u16* __restrict__ K, const u16* __restrict__ V,
    const float* __restrict__ biasT, const float* __restrict__ mask,
    u16* __restrict__ AO)
{
  // per head: [q 64x32 | k 64x32] (4096 u16) -- later overlaid by P [64x64] (swizzled)
  __shared__ u16 qk[NHEAD][4096];
  __shared__ u16 vt[NHEAD][2048];   // vT [32 dims][64 toks] (swizzled rows of 128B)
  const int w = blockIdx.x;
  const int tid = threadIdx.x, wv = tid >> 6, ln = tid & 63;
  const int cl = ln & 15, g = ln >> 4;
  const size_t rb = (size_t)w * SEQ;
  const f32x4 zero4 = {0.f,0.f,0.f,0.f};

  // stage Q,K: 48 x 1KB DMA each
  #pragma unroll
  for(int c=0;c<12;c++){
    int f = wv*12 + c;
    int h = f >> 2, i = f & 3;
    size_t src = (rb + i*16 + (ln>>2))*DIMC + h*HDIM + (ln&3)*8;
    gload_lds16(Q + src, &qk[h][i*512]);
    gload_lds16(K + src, &qk[h][2048 + i*512]);
  }
  // stage V transposed (manual)
  #pragma unroll
  for(int c=0;c<12;c++){
    int ch = c*256 + tid;           // 0..3071 chunks of 8 dims
    int tok = ch / 48, dc = ch % 48;
    union { bf16x8 v; u16 u[8]; } vv;
    vv.v = *(const bf16x8*)(V + (rb + tok)*DIMC + dc*8);
    #pragma unroll
    for(int j=0;j<8;j++){
      int d = dc*8 + j, h = d >> 5, dh = d & 31;
      vt[h][dh*64 + (((tok>>3) ^ (dh&7)) * 8) + (tok & 7)] = vv.u[j];
    }
  }
  __syncthreads();

  const float scale = 0.17677669529663687f;   // 32^-0.5
  #pragma unroll 1
  for(int c=0;c<3;c++){
    const int h = wv*3 + c;
    u16* ph = qk[h];
    bf16x8 aq[4], bk[4];
    #pragma unroll
    for(int i=0;i<4;i++) aq[i] = *(const bf16x8*)&ph[(i*16 + cl)*32 + g*8];
    #pragma unroll
    for(int j=0;j<4;j++) bk[j] = *(const bf16x8*)&ph[2048 + (j*16 + cl)*32 + g*8];
    f32x4 S[4][4];
    #pragma unroll
    for(int i=0;i<4;i++)
      #pragma unroll
      for(int j=0;j<4;j++)
        S[i][j] = mfma_bf16(aq[i], bk[j], zero4);   // K=32: one k-step

    float l[4][4];
    #pragma unroll
    for(int i=0;i<4;i++){
      #pragma unroll
      for(int r=0;r<4;r++){
        int row = i*16 + g*4 + r;
        float v0[4];
        #pragma unroll
        for(int j=0;j<4;j++){
          int col2 = j*16 + cl;
          v0[j] = S[i][j][r]*scale + biasT[h*4096 + row*64 + col2]
                                   + mask[(size_t)w*4096 + row*64 + col2];
        }
        float mx = fmaxf(fmaxf(v0[0],v0[1]), fmaxf(v0[2],v0[3]));
        #pragma unroll
        for(int s=1;s<16;s<<=1) mx = fmaxf(mx, __shfl_xor(mx, s));
        float sm = 0.f;
        #pragma unroll
        for(int j=0;j<4;j++){ v0[j] = __expf(v0[j]-mx); sm += v0[j]; }
        #pragma unroll
        for(int s=1;s<16;s<<=1) sm += __shfl_xor(sm, s);
        l[i][r] = sm;
        // P (unnormalized) -> LDS over q|k slot, A-layout rows of 64 cols, swizzled
        #pragma unroll
        for(int j=0;j<4;j++){
          int col2 = j*16 + cl;
          ph[row*64 + (((col2>>3) ^ (row&7))*8) + (col2&7)] = f2bf(v0[j]);
        }
      }
    }
    // O = P @ V  (64x64 @ 64x32, 2 k-steps)
    f32x4 O[4][2];
    #pragma unroll
    for(int i=0;i<4;i++){ O[i][0] = zero4; O[i][1] = zero4; }
    #pragma unroll
    for(int ks=0;ks<2;ks++){
      bf16x8 ap[4], bv[2];
      #pragma unroll
      for(int i=0;i<4;i++){
        int m = i*16 + cl;
        ap[i] = *(const bf16x8*)&ph[m*64 + (((ks*4+g) ^ (m&7))*8)];
      }
      #pragma unroll
      for(int j=0;j<2;j++){
        int n = j*16 + cl;
        bv[j] = *(const bf16x8*)&vt[h][n*64 + (((ks*4+g) ^ (n&7))*8)];
      }
      #pragma unroll
      for(int i=0;i<4;i++)
        #pragma unroll
        for(int j=0;j<2;j++)
          O[i][j] = mfma_bf16(ap[i], bv[j], O[i][j]);
    }
    #pragma unroll
    for(int i=0;i<4;i++){
      #pragma unroll
      for(int r=0;r<4;r++){
        float inv = 1.0f / l[i][r];
        size_t orow = (rb + i*16 + g*4 + r)*DIMC + h*HDIM;
        AO[orow + cl]      = f2bf(O[i][0][r]*inv);
        AO[orow + 16 + cl] = f2bf(O[i][1][r]*inv);
      }
    }
  }
}

// ---------------- launch ----------------
extern "C" void kernel_launch(void* const* d_in, const int* in_sizes, int n_in,
                              void* d_out, int out_size, void* d_ws, size_t ws_size,
                              hipStream_t stream) {
  const float* x      = (const float*)d_in[0];
  const float* mask   = (const float*)d_in[1];
  const float* qkv_w  = (const float*)d_in[2];
  const float* qkv_b  = (const float*)d_in[3];
  const float* rpb    = (const float*)d_in[4];
  const float* proj_w = (const float*)d_in[5];
  const float* proj_b = (const float*)d_in[6];
  const int*   rpi    = (const int*)d_in[7];

  // ws layout (u16 units): [x_bf16 | v_bf16 | wqT | wpT] then biasT (f32)
  u16* xb  = (u16*)d_ws;                        // NROWS*DIMC, reused as attn-out
  u16* vb  = xb + (size_t)NROWS*DIMC;
  u16* wqT = vb + (size_t)NROWS*DIMC;
  u16* wpT = wqT + (size_t)NQKV*DIMC;
  float* biasT = (float*)(wpT + (size_t)DIMC*DIMC);
  u16* qb = (u16*)d_out;                        // Q,K live in d_out until final GEMM
  u16* kb = qb + (size_t)NROWS*DIMC;
  u16* ao = xb;                                 // attn-out reuses x_bf16 region

  prep_x<<<(NROWS*(size_t)DIMC)/(256*8), 256, 0, stream>>>(x, xb);
  prep_w<<<(NQKV*DIMC + DIMC*DIMC + NHEAD*4096)/256, 256, 0, stream>>>(
      qkv_w, proj_w, rpb, rpi, wqT, wpT, biasT);
  gemm_bt<9,0><<<2048*9, 256, 0, stream>>>(xb, wqT, qkv_b, qb, kb, vb, nullptr);
  attn_win<<<NWIN, 256, 0, stream>>>(qb, kb, vb, biasT, mask, ao);
  gemm_bt<3,1><<<2048*3, 256, 0, stream>>>(ao, wpT, proj_b, nullptr, nullptr, nullptr,
                                           (float*)d_out);
}